// Round 1
// baseline (9709.109 us; speedup 1.0000x reference)
//
#include <hip/hip_runtime.h>
#include <cstddef>

#define NN 1024
#define BB 2
#define TT 12

__device__ __forceinline__ float sigmoidf_(float v) { return 1.0f / (1.0f + expf(-v)); }

// out[b, dstOff + s*dstStep + c, w] = sum_v src[b, srcOff + s*srcStep + c, v] * adj[s,b,w,v]
template<int C, int TW>
__global__ __launch_bounds__(256) void k_diffuse(
    const float* __restrict__ adj, const float* __restrict__ src, float* __restrict__ dst,
    int srcChanTot, int srcOff, int srcStep, int dstChanTot, int dstOff, int dstStep)
{
    constexpr int NG = 256 / TW;              // channel groups
    constexpr int NK = (C + NG - 1) / NG;     // channels per thread
    const int s  = blockIdx.z;
    const int b  = blockIdx.y;
    const int w0 = blockIdx.x * TW;
    const float* A = adj + ((size_t)(s * BB + b)) * NN * NN;
    const float* X = src + ((size_t)(b * srcChanTot + srcOff + s * srcStep)) * NN;
    float*       Y = dst + ((size_t)(b * dstChanTot + dstOff + s * dstStep)) * NN;

    __shared__ __align__(16) float a_s[TW][66];
    __shared__ __align__(16) float x_s[C][66];

    const int tid = threadIdx.x;
    const int tw  = tid % TW;
    const int tg  = tid / TW;

    float acc[NK];
#pragma unroll
    for (int k = 0; k < NK; ++k) acc[k] = 0.f;

    for (int v0 = 0; v0 < NN; v0 += 64) {
#pragma unroll
        for (int r = 0; r < (TW * 64) / 256; ++r) {
            int lin = tid + r * 256;
            int wl = lin >> 6, vl = lin & 63;
            a_s[wl][vl] = A[(size_t)(w0 + wl) * NN + v0 + vl];
        }
        for (int lin = tid; lin < C * 64; lin += 256) {
            int cl = lin >> 6, vl = lin & 63;
            x_s[cl][vl] = X[(size_t)cl * NN + v0 + vl];
        }
        __syncthreads();
#pragma unroll 4
        for (int v2 = 0; v2 < 32; ++v2) {
            float2 av = *reinterpret_cast<const float2*>(&a_s[tw][2 * v2]);
#pragma unroll
            for (int k = 0; k < NK; ++k) {
                int c = tg + NG * k;
                if (c < C) {
                    float2 xv = *reinterpret_cast<const float2*>(&x_s[c][2 * v2]);
                    acc[k] += av.x * xv.x + av.y * xv.y;
                }
            }
        }
        __syncthreads();
    }
#pragma unroll
    for (int k = 0; k < NK; ++k) {
        int c = tg + NG * k;
        if (c < C) Y[(size_t)c * NN + w0 + tw] = acc[k];
    }
}

// xs1 = Wfs.h + bfs ; x1 = mask ? x : xs1 ; x_in = Wdin.[x1,m,h] + bdin
__global__ __launch_bounds__(64) void k_prestep(
    const float* __restrict__ x, const int* __restrict__ mask, const float* __restrict__ h,
    const float* __restrict__ Wfs, const float* __restrict__ bfs,
    const float* __restrict__ Wdin, const float* __restrict__ bdin,
    float* __restrict__ x_in, float* __restrict__ x1buf, float* __restrict__ pred, int t)
{
    const int p = blockIdx.x * 64 + threadIdx.x;
    const int b = p >> 10, n = p & (NN - 1);
    const int ob = blockIdx.y * 4;
    const float* hB = h + (size_t)b * 64 * NN + n;
    const float* w0 = Wdin + (size_t)(ob + 0) * 66 + 2;
    const float* w1 = Wdin + (size_t)(ob + 1) * 66 + 2;
    const float* w2 = Wdin + (size_t)(ob + 2) * 66 + 2;
    const float* w3 = Wdin + (size_t)(ob + 3) * 66 + 2;
    float a0 = 0, a1 = 0, a2 = 0, a3 = 0, xs1 = 0;
#pragma unroll 8
    for (int j = 0; j < 64; ++j) {
        float hv = hB[(size_t)j * NN];
        xs1 += Wfs[j] * hv;
        a0 += w0[j] * hv; a1 += w1[j] * hv; a2 += w2[j] * hv; a3 += w3[j] * hv;
    }
    xs1 += bfs[0];
    const size_t xi = (size_t)(b * NN + n) * TT + t;
    const int   mi = mask[xi];
    const float mf = (float)mi;
    const float x1 = mi ? x[xi] : xs1;
    a0 += w0[-2] * x1 + w0[-1] * mf + bdin[ob + 0];
    a1 += w1[-2] * x1 + w1[-1] * mf + bdin[ob + 1];
    a2 += w2[-2] * x1 + w2[-1] * mf + bdin[ob + 2];
    a3 += w3[-2] * x1 + w3[-1] * mf + bdin[ob + 3];
    float* xo = x_in + (size_t)b * 64 * NN + n;
    xo[(size_t)(ob + 0) * NN] = a0; xo[(size_t)(ob + 1) * NN] = a1;
    xo[(size_t)(ob + 2) * NN] = a2; xo[(size_t)(ob + 3) * NN] = a3;
    if (blockIdx.y == 0) { pred[xi] = xs1; x1buf[p] = x1; }
}

// gc = Wgc.d01 + bgc
__global__ __launch_bounds__(64) void k_gc(
    const float* __restrict__ d01, const float* __restrict__ Wgc, const float* __restrict__ bgc,
    float* __restrict__ gc)
{
    const int p = blockIdx.x * 64 + threadIdx.x;
    const int b = p >> 10, n = p & (NN - 1);
    const int ob = blockIdx.y * 4;
    const float* dB = d01 + (size_t)b * 128 * NN + n;
    const float* w0 = Wgc + (size_t)(ob + 0) * 128;
    const float* w1 = Wgc + (size_t)(ob + 1) * 128;
    const float* w2 = Wgc + (size_t)(ob + 2) * 128;
    const float* w3 = Wgc + (size_t)(ob + 3) * 128;
    float a0 = 0, a1 = 0, a2 = 0, a3 = 0;
#pragma unroll 8
    for (int j = 0; j < 128; ++j) {
        float dv = dB[(size_t)j * NN];
        a0 += w0[j] * dv; a1 += w1[j] * dv; a2 += w2[j] * dv; a3 += w3[j] * dv;
    }
    float* g = gc + (size_t)b * 64 * NN + n;
    g[(size_t)(ob + 0) * NN] = a0 + bgc[ob + 0];
    g[(size_t)(ob + 1) * NN] = a1 + bgc[ob + 1];
    g[(size_t)(ob + 2) * NN] = a2 + bgc[ob + 2];
    g[(size_t)(ob + 3) * NN] = a3 + bgc[ob + 3];
}

// lo = prelu(Wlout.[gc,h] + blout); outbuf=lo; repr = [lo, h]
__global__ __launch_bounds__(64) void k_dec2(
    const float* __restrict__ gc, const float* __restrict__ h,
    const float* __restrict__ Wlout, const float* __restrict__ blout,
    const float* __restrict__ prelu_a,
    float* __restrict__ outbuf, float* __restrict__ repr, int t)
{
    const int p = blockIdx.x * 64 + threadIdx.x;
    const int b = p >> 10, n = p & (NN - 1);
    const int ob = blockIdx.y * 4;
    const float* gB = gc + (size_t)b * 64 * NN + n;
    const float* hB = h + (size_t)b * 64 * NN + n;
    const float* w0 = Wlout + (size_t)(ob + 0) * 128;
    const float* w1 = Wlout + (size_t)(ob + 1) * 128;
    const float* w2 = Wlout + (size_t)(ob + 2) * 128;
    const float* w3 = Wlout + (size_t)(ob + 3) * 128;
    float a0 = 0, a1 = 0, a2 = 0, a3 = 0;
#pragma unroll 8
    for (int j = 0; j < 64; ++j) {
        float gv = gB[(size_t)j * NN];
        a0 += w0[j] * gv; a1 += w1[j] * gv; a2 += w2[j] * gv; a3 += w3[j] * gv;
    }
#pragma unroll 8
    for (int j = 0; j < 64; ++j) {
        float hv = hB[(size_t)j * NN];
        a0 += w0[64 + j] * hv; a1 += w1[64 + j] * hv; a2 += w2[64 + j] * hv; a3 += w3[64 + j] * hv;
    }
    const float pa = prelu_a[0];
    float vq[4] = { a0 + blout[ob + 0], a1 + blout[ob + 1], a2 + blout[ob + 2], a3 + blout[ob + 3] };
#pragma unroll
    for (int q = 0; q < 4; ++q) {
        float v = vq[q];
        v = (v >= 0.f) ? v : pa * v;
        outbuf[(size_t)(b * 64 + ob + q) * NN + n] = v;
        repr[(((size_t)b * 128 + ob + q) * NN + n) * TT + t] = v;
        repr[(((size_t)b * 128 + 64 + ob + q) * NN + n) * TT + t] = hB[(size_t)(ob + q) * NN];
    }
}

// xs2 = Wro.[out,h] + bro (imputation); x2 = mask ? x1 : xs2; assemble xh -> z[0..65]
__global__ __launch_bounds__(64) void k_xs2(
    const float* __restrict__ outbuf, const float* __restrict__ h,
    const float* __restrict__ Wro, const float* __restrict__ bro,
    const float* __restrict__ x1buf, const float* __restrict__ x, const int* __restrict__ mask,
    float* __restrict__ imp, float* __restrict__ z, int t)
{
    const int p = blockIdx.x * 64 + threadIdx.x;
    const int b = p >> 10, n = p & (NN - 1);
    const float* oB = outbuf + (size_t)b * 64 * NN + n;
    const float* hB = h + (size_t)b * 64 * NN + n;
    float acc = 0;
#pragma unroll 8
    for (int j = 0; j < 64; ++j) acc += Wro[j] * oB[(size_t)j * NN];
#pragma unroll 8
    for (int j = 0; j < 64; ++j) acc += Wro[64 + j] * hB[(size_t)j * NN];
    const float xs2 = acc + bro[0];
    const size_t xi = (size_t)(b * NN + n) * TT + t;
    imp[xi] = xs2;
    const int mi = mask[xi];
    const float x2 = mi ? x1buf[p] : xs2;
    float* zB = z + (size_t)b * 330 * NN + n;
    zB[0] = x2;
    zB[NN] = (float)mi;
#pragma unroll 8
    for (int j = 0; j < 64; ++j) zB[(size_t)(2 + j) * NN] = hB[(size_t)j * NN];
}

// r,u = sigmoid(W{r,u}.z + b); zc[0..1]=inp_c; zc[2..65]=r*h; store u
__global__ __launch_bounds__(64) void k_gates(
    const float* __restrict__ z, const float* __restrict__ h,
    const float* __restrict__ Wr, const float* __restrict__ br,
    const float* __restrict__ Wu, const float* __restrict__ bu,
    float* __restrict__ ubuf, float* __restrict__ zc)
{
    const int p = blockIdx.x * 64 + threadIdx.x;
    const int b = p >> 10, n = p & (NN - 1);
    const int ob = blockIdx.y * 4;
    const float* zB = z + (size_t)b * 330 * NN + n;
    const float* wr0 = Wr + (size_t)(ob + 0) * 330;
    const float* wr1 = Wr + (size_t)(ob + 1) * 330;
    const float* wr2 = Wr + (size_t)(ob + 2) * 330;
    const float* wr3 = Wr + (size_t)(ob + 3) * 330;
    const float* wu0 = Wu + (size_t)(ob + 0) * 330;
    const float* wu1 = Wu + (size_t)(ob + 1) * 330;
    const float* wu2 = Wu + (size_t)(ob + 2) * 330;
    const float* wu3 = Wu + (size_t)(ob + 3) * 330;
    float r0 = 0, r1 = 0, r2 = 0, r3 = 0, u0 = 0, u1 = 0, u2 = 0, u3 = 0;
#pragma unroll 2
    for (int j = 0; j < 330; ++j) {
        float zv = zB[(size_t)j * NN];
        r0 += wr0[j] * zv; r1 += wr1[j] * zv; r2 += wr2[j] * zv; r3 += wr3[j] * zv;
        u0 += wu0[j] * zv; u1 += wu1[j] * zv; u2 += wu2[j] * zv; u3 += wu3[j] * zv;
    }
    float* zcB = zc + (size_t)b * 330 * NN + n;
    float rr[4] = { r0, r1, r2, r3 };
    float uu[4] = { u0, u1, u2, u3 };
#pragma unroll
    for (int q = 0; q < 4; ++q) {
        float r = sigmoidf_(rr[q] + br[ob + q]);
        float u = sigmoidf_(uu[q] + bu[ob + q]);
        size_t hidx = (size_t)(b * 64 + ob + q) * NN + n;
        ubuf[hidx] = u;
        zcB[(size_t)(2 + ob + q) * NN] = r * h[hidx];
    }
    if (blockIdx.y == 0) { zcB[0] = zB[0]; zcB[NN] = zB[NN]; }
}

// c = tanh(Wc.zc + bc); h = u*h + (1-u)*c
__global__ __launch_bounds__(64) void k_cell(
    const float* __restrict__ zc, const float* __restrict__ ubuf,
    const float* __restrict__ Wc, const float* __restrict__ bc,
    float* __restrict__ h)
{
    const int p = blockIdx.x * 64 + threadIdx.x;
    const int b = p >> 10, n = p & (NN - 1);
    const int ob = blockIdx.y * 4;
    const float* zB = zc + (size_t)b * 330 * NN + n;
    const float* w0 = Wc + (size_t)(ob + 0) * 330;
    const float* w1 = Wc + (size_t)(ob + 1) * 330;
    const float* w2 = Wc + (size_t)(ob + 2) * 330;
    const float* w3 = Wc + (size_t)(ob + 3) * 330;
    float a0 = 0, a1 = 0, a2 = 0, a3 = 0;
#pragma unroll 2
    for (int j = 0; j < 330; ++j) {
        float zv = zB[(size_t)j * NN];
        a0 += w0[j] * zv; a1 += w1[j] * zv; a2 += w2[j] * zv; a3 += w3[j] * zv;
    }
    float aa[4] = { a0, a1, a2, a3 };
#pragma unroll
    for (int q = 0; q < 4; ++q) {
        float c = tanhf(aa[q] + bc[ob + q]);
        size_t idx = (size_t)(b * 64 + ob + q) * NN + n;
        float u = ubuf[idx];
        h[idx] = u * h[idx] + (1.f - u) * c;
    }
}

extern "C" void kernel_launch(void* const* d_in, const int* in_sizes, int n_in,
                              void* d_out, int out_size, void* d_ws, size_t ws_size,
                              hipStream_t stream)
{
    const float* x     = (const float*)d_in[0];
    const int*   mask  = (const int*)  d_in[1];
    const float* adj   = (const float*)d_in[2];
    const float* Wr    = (const float*)d_in[3];
    const float* br    = (const float*)d_in[4];
    const float* Wu    = (const float*)d_in[5];
    const float* bu    = (const float*)d_in[6];
    const float* Wc    = (const float*)d_in[7];
    const float* bc    = (const float*)d_in[8];
    const float* Wfs   = (const float*)d_in[9];
    const float* bfs   = (const float*)d_in[10];
    const float* Wdin  = (const float*)d_in[11];
    const float* bdin  = (const float*)d_in[12];
    const float* Wgc   = (const float*)d_in[13];
    const float* bgc   = (const float*)d_in[14];
    const float* Wlout = (const float*)d_in[15];
    const float* blout = (const float*)d_in[16];
    const float* Wro   = (const float*)d_in[17];
    const float* bro   = (const float*)d_in[18];
    const float* pa    = (const float*)d_in[19];

    float* ws  = (float*)d_ws;
    float* h   = ws;                 // B*64*N      = 131072
    float* xin = ws + 131072;        // B*64*N (also gc buffer)
    float* d01 = ws + 262144;        // B*128*N (also decoder-out buffer)
    float* x1b = ws + 524288;        // B*N
    float* z   = ws + 526336;        // B*330*N
    float* zc  = ws + 1202176;       // B*330*N
    float* ub  = ws + 1878016;       // B*64*N  (total 2009088 floats = 8.04 MB)

    float* imp  = (float*)d_out;
    float* pred = imp + (size_t)BB * NN * TT;
    float* repr = imp + (size_t)2 * BB * NN * TT;

    hipMemsetAsync(h, 0, (size_t)BB * 64 * NN * sizeof(float), stream);

    for (int t = 0; t < TT; ++t) {
        hipLaunchKernelGGL(k_prestep, dim3(32, 16), dim3(64), 0, stream,
                           x, mask, h, Wfs, bfs, Wdin, bdin, xin, x1b, pred, t);
        hipLaunchKernelGGL((k_diffuse<64, 16>), dim3(64, BB, 2), dim3(256), 0, stream,
                           adj, xin, d01, 64, 0, 0, 128, 0, 64);
        hipLaunchKernelGGL(k_gc, dim3(32, 16), dim3(64), 0, stream, d01, Wgc, bgc, xin);
        hipLaunchKernelGGL(k_dec2, dim3(32, 16), dim3(64), 0, stream,
                           xin, h, Wlout, blout, pa, d01, repr, t);
        hipLaunchKernelGGL(k_xs2, dim3(32), dim3(64), 0, stream,
                           d01, h, Wro, bro, x1b, x, mask, imp, z, t);
        hipLaunchKernelGGL((k_diffuse<66, 16>), dim3(64, BB, 2), dim3(256), 0, stream,
                           adj, z, z, 330, 0, 0, 330, 66, 132);
        hipLaunchKernelGGL((k_diffuse<66, 16>), dim3(64, BB, 2), dim3(256), 0, stream,
                           adj, z, z, 330, 66, 132, 330, 132, 132);
        hipLaunchKernelGGL(k_gates, dim3(32, 16), dim3(64), 0, stream,
                           z, h, Wr, br, Wu, bu, ub, zc);
        hipLaunchKernelGGL((k_diffuse<66, 16>), dim3(64, BB, 2), dim3(256), 0, stream,
                           adj, zc, zc, 330, 0, 0, 330, 66, 132);
        hipLaunchKernelGGL((k_diffuse<66, 16>), dim3(64, BB, 2), dim3(256), 0, stream,
                           adj, zc, zc, 330, 66, 132, 330, 132, 132);
        hipLaunchKernelGGL(k_cell, dim3(32, 16), dim3(64), 0, stream, zc, ub, Wc, bc, h);
    }
}

// Round 2
// 3961.113 us; speedup vs baseline: 2.4511x; 2.4511x over previous
//
#include <hip/hip_runtime.h>
#include <cstddef>

#define NN 1024
#define BB 2
#define TT 12
#define VS 4   // V-split factor for diffusion

__device__ __forceinline__ float sigmoidf_(float v) { return 1.0f / (1.0f + expf(-v)); }

// Partial diffusion over a V-chunk:
// part[((vc*4 + s*2+b)*C + c)*NN + w] = sum_{v in chunk} src[b, srcOff + s*srcStep + c, v] * adj[s,b,w,v]
template<int C, int TW>
__global__ __launch_bounds__(256) void k_diffuse(
    const float* __restrict__ adj, const float* __restrict__ src, float* __restrict__ part,
    int srcChanTot, int srcOff, int srcStep)
{
    constexpr int NG = 256 / TW;              // 16 channel groups
    constexpr int NK = (C + NG - 1) / NG;     // channels per thread
    const int sb = blockIdx.y;                // s*2+b
    const int s  = sb >> 1, b = sb & 1;
    const int w0 = blockIdx.x * TW;
    const int vbase = blockIdx.z * (NN / VS);
    const float* A = adj + ((size_t)(s * BB + b)) * NN * NN;
    const float* X = src + ((size_t)(b * srcChanTot + srcOff + s * srcStep)) * NN;
    float*       P = part + ((size_t)(blockIdx.z * 4 + sb) * C) * NN;

    __shared__ __align__(16) float a_s[TW][66];
    __shared__ __align__(16) float x_s[C][66];

    const int tid = threadIdx.x;
    const int tw  = tid % TW;
    const int tg  = tid / TW;

    float acc[NK];
#pragma unroll
    for (int k = 0; k < NK; ++k) acc[k] = 0.f;

    for (int v0 = vbase; v0 < vbase + NN / VS; v0 += 64) {
#pragma unroll
        for (int r = 0; r < (TW * 64) / 256; ++r) {
            int lin = tid + r * 256;
            int wl = lin >> 6, vl = lin & 63;
            a_s[wl][vl] = A[(size_t)(w0 + wl) * NN + v0 + vl];
        }
        for (int lin = tid; lin < C * 64; lin += 256) {
            int cl = lin >> 6, vl = lin & 63;
            x_s[cl][vl] = X[(size_t)cl * NN + v0 + vl];
        }
        __syncthreads();
#pragma unroll 4
        for (int v2 = 0; v2 < 32; ++v2) {
            float2 av = *reinterpret_cast<const float2*>(&a_s[tw][2 * v2]);
#pragma unroll
            for (int k = 0; k < NK; ++k) {
                int c = tg * NK + k;          // simultaneous c differ by NK -> distinct banks
                if (c < C) {
                    float2 xv = *reinterpret_cast<const float2*>(&x_s[c][2 * v2]);
                    acc[k] += av.x * xv.x + av.y * xv.y;
                }
            }
        }
        __syncthreads();
    }
#pragma unroll
    for (int k = 0; k < NK; ++k) {
        int c = tg * NK + k;
        if (c < C) P[(size_t)c * NN + w0 + tw] = acc[k];
    }
}

// dst[b, dstOff + s*dstStep + c, w] = sum_vc part[((vc*4+sb)*C + c)*NN + w]
__global__ __launch_bounds__(256) void k_reduce(
    const float* __restrict__ part, float* __restrict__ dst,
    int C, int dstChanTot, int dstOff, int dstStep)
{
    const int idx = blockIdx.x * 256 + threadIdx.x;
    const int total = 4 * C * NN;
    if (idx >= total) return;
    const int w = idx & (NN - 1);
    const int rest = idx >> 10;
    const int c = rest % C;
    const int sb = rest / C;
    const int s = sb >> 1, b = sb & 1;
    float acc = 0.f;
#pragma unroll
    for (int vc = 0; vc < VS; ++vc)
        acc += part[((size_t)(vc * 4 + sb) * C + c) * NN + w];
    dst[((size_t)(b * dstChanTot + dstOff + s * dstStep) + c) * NN + w] = acc;
}

// xs1 = Wfs.h + bfs ; x1 = mask ? x : xs1 ; x_in = Wdin.[x1,m,h] + bdin
__global__ __launch_bounds__(256) void k_prestep(
    const float* __restrict__ x, const int* __restrict__ mask, const float* __restrict__ h,
    const float* __restrict__ Wfs, const float* __restrict__ bfs,
    const float* __restrict__ Wdin, const float* __restrict__ bdin,
    float* __restrict__ x_in, float* __restrict__ x1buf, float* __restrict__ pred, int t)
{
    const int p = blockIdx.x * 256 + threadIdx.x;
    const int b = p >> 10, n = p & (NN - 1);
    const int ob = blockIdx.y * 4;
    const float* hB = h + (size_t)b * 64 * NN + n;
    const float* w0 = Wdin + (size_t)(ob + 0) * 66 + 2;
    const float* w1 = Wdin + (size_t)(ob + 1) * 66 + 2;
    const float* w2 = Wdin + (size_t)(ob + 2) * 66 + 2;
    const float* w3 = Wdin + (size_t)(ob + 3) * 66 + 2;
    float a0 = 0, a1 = 0, a2 = 0, a3 = 0, xs1 = 0;
#pragma unroll 8
    for (int j = 0; j < 64; ++j) {
        float hv = hB[(size_t)j * NN];
        xs1 += Wfs[j] * hv;
        a0 += w0[j] * hv; a1 += w1[j] * hv; a2 += w2[j] * hv; a3 += w3[j] * hv;
    }
    xs1 += bfs[0];
    const size_t xi = (size_t)(b * NN + n) * TT + t;
    const int   mi = mask[xi];
    const float mf = (float)mi;
    const float x1 = mi ? x[xi] : xs1;
    a0 += w0[-2] * x1 + w0[-1] * mf + bdin[ob + 0];
    a1 += w1[-2] * x1 + w1[-1] * mf + bdin[ob + 1];
    a2 += w2[-2] * x1 + w2[-1] * mf + bdin[ob + 2];
    a3 += w3[-2] * x1 + w3[-1] * mf + bdin[ob + 3];
    float* xo = x_in + (size_t)b * 64 * NN + n;
    xo[(size_t)(ob + 0) * NN] = a0; xo[(size_t)(ob + 1) * NN] = a1;
    xo[(size_t)(ob + 2) * NN] = a2; xo[(size_t)(ob + 3) * NN] = a3;
    if (blockIdx.y == 0) { pred[xi] = xs1; x1buf[p] = x1; }
}

// gc = Wgc.d01 + bgc
__global__ __launch_bounds__(256) void k_gc(
    const float* __restrict__ d01, const float* __restrict__ Wgc, const float* __restrict__ bgc,
    float* __restrict__ gc)
{
    const int p = blockIdx.x * 256 + threadIdx.x;
    const int b = p >> 10, n = p & (NN - 1);
    const int ob = blockIdx.y * 4;
    const float* dB = d01 + (size_t)b * 128 * NN + n;
    const float* w0 = Wgc + (size_t)(ob + 0) * 128;
    const float* w1 = Wgc + (size_t)(ob + 1) * 128;
    const float* w2 = Wgc + (size_t)(ob + 2) * 128;
    const float* w3 = Wgc + (size_t)(ob + 3) * 128;
    float a0 = 0, a1 = 0, a2 = 0, a3 = 0;
#pragma unroll 8
    for (int j = 0; j < 128; ++j) {
        float dv = dB[(size_t)j * NN];
        a0 += w0[j] * dv; a1 += w1[j] * dv; a2 += w2[j] * dv; a3 += w3[j] * dv;
    }
    float* g = gc + (size_t)b * 64 * NN + n;
    g[(size_t)(ob + 0) * NN] = a0 + bgc[ob + 0];
    g[(size_t)(ob + 1) * NN] = a1 + bgc[ob + 1];
    g[(size_t)(ob + 2) * NN] = a2 + bgc[ob + 2];
    g[(size_t)(ob + 3) * NN] = a3 + bgc[ob + 3];
}

// lo = prelu(Wlout.[gc,h] + blout); outbuf=lo; repr = [lo, h]
__global__ __launch_bounds__(256) void k_dec2(
    const float* __restrict__ gc, const float* __restrict__ h,
    const float* __restrict__ Wlout, const float* __restrict__ blout,
    const float* __restrict__ prelu_a,
    float* __restrict__ outbuf, float* __restrict__ repr, int t)
{
    const int p = blockIdx.x * 256 + threadIdx.x;
    const int b = p >> 10, n = p & (NN - 1);
    const int ob = blockIdx.y * 4;
    const float* gB = gc + (size_t)b * 64 * NN + n;
    const float* hB = h + (size_t)b * 64 * NN + n;
    const float* w0 = Wlout + (size_t)(ob + 0) * 128;
    const float* w1 = Wlout + (size_t)(ob + 1) * 128;
    const float* w2 = Wlout + (size_t)(ob + 2) * 128;
    const float* w3 = Wlout + (size_t)(ob + 3) * 128;
    float a0 = 0, a1 = 0, a2 = 0, a3 = 0;
#pragma unroll 8
    for (int j = 0; j < 64; ++j) {
        float gv = gB[(size_t)j * NN];
        a0 += w0[j] * gv; a1 += w1[j] * gv; a2 += w2[j] * gv; a3 += w3[j] * gv;
    }
#pragma unroll 8
    for (int j = 0; j < 64; ++j) {
        float hv = hB[(size_t)j * NN];
        a0 += w0[64 + j] * hv; a1 += w1[64 + j] * hv; a2 += w2[64 + j] * hv; a3 += w3[64 + j] * hv;
    }
    const float pa = prelu_a[0];
    float vq[4] = { a0 + blout[ob + 0], a1 + blout[ob + 1], a2 + blout[ob + 2], a3 + blout[ob + 3] };
#pragma unroll
    for (int q = 0; q < 4; ++q) {
        float v = vq[q];
        v = (v >= 0.f) ? v : pa * v;
        outbuf[(size_t)(b * 64 + ob + q) * NN + n] = v;
        repr[(((size_t)b * 128 + ob + q) * NN + n) * TT + t] = v;
        repr[(((size_t)b * 128 + 64 + ob + q) * NN + n) * TT + t] = hB[(size_t)(ob + q) * NN];
    }
}

// xs2 = Wro.[out,h] + bro (imputation); x2 = mask ? x1 : xs2; assemble xh -> z[0..65]
__global__ __launch_bounds__(256) void k_xs2(
    const float* __restrict__ outbuf, const float* __restrict__ h,
    const float* __restrict__ Wro, const float* __restrict__ bro,
    const float* __restrict__ x1buf, const float* __restrict__ x, const int* __restrict__ mask,
    float* __restrict__ imp, float* __restrict__ z, int t)
{
    const int p = blockIdx.x * 256 + threadIdx.x;
    const int b = p >> 10, n = p & (NN - 1);
    const float* oB = outbuf + (size_t)b * 64 * NN + n;
    const float* hB = h + (size_t)b * 64 * NN + n;
    float acc = 0;
#pragma unroll 8
    for (int j = 0; j < 64; ++j) acc += Wro[j] * oB[(size_t)j * NN];
#pragma unroll 8
    for (int j = 0; j < 64; ++j) acc += Wro[64 + j] * hB[(size_t)j * NN];
    const float xs2 = acc + bro[0];
    const size_t xi = (size_t)(b * NN + n) * TT + t;
    imp[xi] = xs2;
    const int mi = mask[xi];
    const float x2 = mi ? x1buf[p] : xs2;
    float* zB = z + (size_t)b * 330 * NN + n;
    zB[0] = x2;
    zB[NN] = (float)mi;
#pragma unroll 8
    for (int j = 0; j < 64; ++j) zB[(size_t)(2 + j) * NN] = hB[(size_t)j * NN];
}

// r,u = sigmoid(W{r,u}.z + b); zc[0..1]=inp_c; zc[2..65]=r*h; store u
__global__ __launch_bounds__(256) void k_gates(
    const float* __restrict__ z, const float* __restrict__ h,
    const float* __restrict__ Wr, const float* __restrict__ br,
    const float* __restrict__ Wu, const float* __restrict__ bu,
    float* __restrict__ ubuf, float* __restrict__ zc)
{
    const int p = blockIdx.x * 256 + threadIdx.x;
    const int b = p >> 10, n = p & (NN - 1);
    const int ob = blockIdx.y * 4;
    const float* zB = z + (size_t)b * 330 * NN + n;
    const float* wr0 = Wr + (size_t)(ob + 0) * 330;
    const float* wr1 = Wr + (size_t)(ob + 1) * 330;
    const float* wr2 = Wr + (size_t)(ob + 2) * 330;
    const float* wr3 = Wr + (size_t)(ob + 3) * 330;
    const float* wu0 = Wu + (size_t)(ob + 0) * 330;
    const float* wu1 = Wu + (size_t)(ob + 1) * 330;
    const float* wu2 = Wu + (size_t)(ob + 2) * 330;
    const float* wu3 = Wu + (size_t)(ob + 3) * 330;
    float r0 = 0, r1 = 0, r2 = 0, r3 = 0, u0 = 0, u1 = 0, u2 = 0, u3 = 0;
#pragma unroll 2
    for (int j = 0; j < 330; ++j) {
        float zv = zB[(size_t)j * NN];
        r0 += wr0[j] * zv; r1 += wr1[j] * zv; r2 += wr2[j] * zv; r3 += wr3[j] * zv;
        u0 += wu0[j] * zv; u1 += wu1[j] * zv; u2 += wu2[j] * zv; u3 += wu3[j] * zv;
    }
    float* zcB = zc + (size_t)b * 330 * NN + n;
    float rr[4] = { r0, r1, r2, r3 };
    float uu[4] = { u0, u1, u2, u3 };
#pragma unroll
    for (int q = 0; q < 4; ++q) {
        float r = sigmoidf_(rr[q] + br[ob + q]);
        float u = sigmoidf_(uu[q] + bu[ob + q]);
        size_t hidx = (size_t)(b * 64 + ob + q) * NN + n;
        ubuf[hidx] = u;
        zcB[(size_t)(2 + ob + q) * NN] = r * h[hidx];
    }
    if (blockIdx.y == 0) { zcB[0] = zB[0]; zcB[NN] = zB[NN]; }
}

// c = tanh(Wc.zc + bc); h = u*h + (1-u)*c
__global__ __launch_bounds__(256) void k_cell(
    const float* __restrict__ zc, const float* __restrict__ ubuf,
    const float* __restrict__ Wc, const float* __restrict__ bc,
    float* __restrict__ h)
{
    const int p = blockIdx.x * 256 + threadIdx.x;
    const int b = p >> 10, n = p & (NN - 1);
    const int ob = blockIdx.y * 4;
    const float* zB = zc + (size_t)b * 330 * NN + n;
    const float* w0 = Wc + (size_t)(ob + 0) * 330;
    const float* w1 = Wc + (size_t)(ob + 1) * 330;
    const float* w2 = Wc + (size_t)(ob + 2) * 330;
    const float* w3 = Wc + (size_t)(ob + 3) * 330;
    float a0 = 0, a1 = 0, a2 = 0, a3 = 0;
#pragma unroll 2
    for (int j = 0; j < 330; ++j) {
        float zv = zB[(size_t)j * NN];
        a0 += w0[j] * zv; a1 += w1[j] * zv; a2 += w2[j] * zv; a3 += w3[j] * zv;
    }
    float aa[4] = { a0, a1, a2, a3 };
#pragma unroll
    for (int q = 0; q < 4; ++q) {
        float c = tanhf(aa[q] + bc[ob + q]);
        size_t idx = (size_t)(b * 64 + ob + q) * NN + n;
        float u = ubuf[idx];
        h[idx] = u * h[idx] + (1.f - u) * c;
    }
}

extern "C" void kernel_launch(void* const* d_in, const int* in_sizes, int n_in,
                              void* d_out, int out_size, void* d_ws, size_t ws_size,
                              hipStream_t stream)
{
    const float* x     = (const float*)d_in[0];
    const int*   mask  = (const int*)  d_in[1];
    const float* adj   = (const float*)d_in[2];
    const float* Wr    = (const float*)d_in[3];
    const float* br    = (const float*)d_in[4];
    const float* Wu    = (const float*)d_in[5];
    const float* bu    = (const float*)d_in[6];
    const float* Wc    = (const float*)d_in[7];
    const float* bc    = (const float*)d_in[8];
    const float* Wfs   = (const float*)d_in[9];
    const float* bfs   = (const float*)d_in[10];
    const float* Wdin  = (const float*)d_in[11];
    const float* bdin  = (const float*)d_in[12];
    const float* Wgc   = (const float*)d_in[13];
    const float* bgc   = (const float*)d_in[14];
    const float* Wlout = (const float*)d_in[15];
    const float* blout = (const float*)d_in[16];
    const float* Wro   = (const float*)d_in[17];
    const float* bro   = (const float*)d_in[18];
    const float* pa    = (const float*)d_in[19];

    float* ws  = (float*)d_ws;
    float* h    = ws;                 // B*64*N      = 131072
    float* xin  = ws + 131072;        // B*64*N (also gc buffer)
    float* d01  = ws + 262144;        // B*128*N (also decoder-out buffer)
    float* x1b  = ws + 524288;        // B*N
    float* z    = ws + 526336;        // B*330*N
    float* zc   = ws + 1202176;       // B*330*N
    float* ub   = ws + 1878016;       // B*64*N
    float* part = ws + 2009088;       // VS*4*66*N = 1081344 floats (total ~12.4 MB)

    float* imp  = (float*)d_out;
    float* pred = imp + (size_t)BB * NN * TT;
    float* repr = imp + (size_t)2 * BB * NN * TT;

    hipMemsetAsync(h, 0, (size_t)BB * 64 * NN * sizeof(float), stream);

    const dim3 gD(NN / 16, 4, VS);   // diffuse grid: 64 w-tiles x (s,b) x v-chunks
    const dim3 bD(256);
    const int gR66 = (4 * 66 * NN + 255) / 256;
    const int gR64 = (4 * 64 * NN + 255) / 256;

    for (int t = 0; t < TT; ++t) {
        hipLaunchKernelGGL(k_prestep, dim3(8, 16), dim3(256), 0, stream,
                           x, mask, h, Wfs, bfs, Wdin, bdin, xin, x1b, pred, t);
        hipLaunchKernelGGL((k_diffuse<64, 16>), gD, bD, 0, stream, adj, xin, part, 64, 0, 0);
        hipLaunchKernelGGL(k_reduce, dim3(gR64), dim3(256), 0, stream, part, d01, 64, 128, 0, 64);
        hipLaunchKernelGGL(k_gc, dim3(8, 16), dim3(256), 0, stream, d01, Wgc, bgc, xin);
        hipLaunchKernelGGL(k_dec2, dim3(8, 16), dim3(256), 0, stream,
                           xin, h, Wlout, blout, pa, d01, repr, t);
        hipLaunchKernelGGL(k_xs2, dim3(8), dim3(256), 0, stream,
                           d01, h, Wro, bro, x1b, x, mask, imp, z, t);
        hipLaunchKernelGGL((k_diffuse<66, 16>), gD, bD, 0, stream, adj, z, part, 330, 0, 0);
        hipLaunchKernelGGL(k_reduce, dim3(gR66), dim3(256), 0, stream, part, z, 66, 330, 66, 132);
        hipLaunchKernelGGL((k_diffuse<66, 16>), gD, bD, 0, stream, adj, z, part, 330, 66, 132);
        hipLaunchKernelGGL(k_reduce, dim3(gR66), dim3(256), 0, stream, part, z, 66, 330, 132, 132);
        hipLaunchKernelGGL(k_gates, dim3(8, 16), dim3(256), 0, stream,
                           z, h, Wr, br, Wu, bu, ub, zc);
        hipLaunchKernelGGL((k_diffuse<66, 16>), gD, bD, 0, stream, adj, zc, part, 330, 0, 0);
        hipLaunchKernelGGL(k_reduce, dim3(gR66), dim3(256), 0, stream, part, zc, 66, 330, 66, 132);
        hipLaunchKernelGGL((k_diffuse<66, 16>), gD, bD, 0, stream, adj, zc, part, 330, 66, 132);
        hipLaunchKernelGGL(k_reduce, dim3(gR66), dim3(256), 0, stream, part, zc, 66, 330, 132, 132);
        hipLaunchKernelGGL(k_cell, dim3(8, 16), dim3(256), 0, stream, zc, ub, Wc, bc, h);
    }
}

// Round 3
// 2117.922 us; speedup vs baseline: 4.5843x; 1.8703x over previous
//
#include <hip/hip_runtime.h>
#include <hip/hip_bf16.h>
#include <cstddef>

#define NN 1024
#define BB 2
#define TT 12

typedef __attribute__((ext_vector_type(8))) short short8;
typedef __attribute__((ext_vector_type(4))) float f32x4;

__device__ __forceinline__ float sigmoidf_(float v) { return 1.0f / (1.0f + expf(-v)); }

// Convert adj (2*B*N*N fp32) to bf16 once per call.
__global__ __launch_bounds__(256) void k_cvt_adj(const float* __restrict__ a,
                                                 __hip_bfloat16* __restrict__ ab)
{
    size_t i = ((size_t)blockIdx.x * 256 + threadIdx.x) * 4;
    float4 v = *reinterpret_cast<const float4*>(a + i);
    ab[i + 0] = __float2bfloat16(v.x);
    ab[i + 1] = __float2bfloat16(v.y);
    ab[i + 2] = __float2bfloat16(v.z);
    ab[i + 3] = __float2bfloat16(v.w);
}

// MFMA diffusion: dst[c][w] = sum_v src[c][v] * adj[sb][w][v]
// A-operand = src rows (M=c), B-operand = adj rows (K=v, N=w). Both 16B bf16 loads.
// grid: (16 n-tiles of 64, 4 sb). block: 256 = 4 waves, each wave 16 w-columns.
template<int C>
__global__ __launch_bounds__(256) void k_dif(
    const __hip_bfloat16* __restrict__ adjb,
    const __hip_bfloat16* __restrict__ srcb, int srcCT, int srcOff, int srcStep,
    float* __restrict__ dstf, int dstfCT, int dstfOff, int dstfStep,
    __hip_bfloat16* __restrict__ dstb, int dstbCT, int dstbOff, int dstbStep)
{
    constexpr int MT = (C + 15) / 16;
    const int sb = blockIdx.y;
    const int s = sb >> 1, b = sb & 1;
    const int wave = threadIdx.x >> 6, lane = threadIdx.x & 63;
    const int lr = lane & 15, lq = lane >> 4;
    const int n0 = blockIdx.x * 64 + wave * 16;

    const __hip_bfloat16* A = adjb + ((size_t)sb << 20) + (size_t)(n0 + lr) * NN + lq * 8;
    const __hip_bfloat16* X = srcb + ((size_t)(b * srcCT + srcOff + s * srcStep + lr)) * NN + lq * 8;

    f32x4 acc[MT];
#pragma unroll
    for (int m = 0; m < MT; ++m) acc[m] = (f32x4){0.f, 0.f, 0.f, 0.f};

    const short8 zsh = {0, 0, 0, 0, 0, 0, 0, 0};
#pragma unroll 4
    for (int v0 = 0; v0 < NN; v0 += 32) {
        short8 bf = *reinterpret_cast<const short8*>(A + v0);
        short8 af[MT];
#pragma unroll
        for (int m = 0; m < MT; ++m) {
            short8 tv = *reinterpret_cast<const short8*>(X + (size_t)m * 16 * NN + v0);
            if ((C & 15) != 0 && m == MT - 1 && lr >= (C & 15)) tv = zsh;
            af[m] = tv;
        }
#pragma unroll
        for (int m = 0; m < MT; ++m)
            acc[m] = __builtin_amdgcn_mfma_f32_16x16x32_bf16(af[m], bf, acc[m], 0, 0, 0);
    }

    const size_t dbF = (size_t)(b * dstfCT + dstfOff + s * dstfStep);
    const size_t dbB = dstb ? (size_t)(b * dstbCT + dstbOff + s * dstbStep) : 0;
#pragma unroll
    for (int m = 0; m < MT; ++m) {
#pragma unroll
        for (int q = 0; q < 4; ++q) {
            int c = m * 16 + lq * 4 + q;
            if (c < C) {
                float val = acc[m][q];
                dstf[(dbF + c) * NN + n0 + lr] = val;
                if (dstb) dstb[(dbB + c) * NN + n0 + lr] = __float2bfloat16(val);
            }
        }
    }
}

// xs1 = Wfs.h + bfs ; x1 = mask ? x : xs1 ; xin_bf16[oc] = Wdin.[x1,m,h] + bdin
// grid (8, 64): thread = (b,n), oc = blockIdx.y
__global__ __launch_bounds__(256) void k_prestep(
    const float* __restrict__ x, const int* __restrict__ mask, const float* __restrict__ h,
    const float* __restrict__ Wfs, const float* __restrict__ bfs,
    const float* __restrict__ Wdin, const float* __restrict__ bdin,
    __hip_bfloat16* __restrict__ xinb, float* __restrict__ x1buf, float* __restrict__ pred, int t)
{
    const int p = blockIdx.x * 256 + threadIdx.x;
    const int b = p >> 10, n = p & (NN - 1);
    const int oc = blockIdx.y;
    const float* hB = h + (size_t)b * 64 * NN + n;
    const float* w = Wdin + (size_t)oc * 66;
    float a = 0.f, xs1 = 0.f;
#pragma unroll 8
    for (int j = 0; j < 64; ++j) {
        float hv = hB[(size_t)j * NN];
        xs1 += Wfs[j] * hv;
        a += w[2 + j] * hv;
    }
    xs1 += bfs[0];
    const size_t xi = (size_t)(b * NN + n) * TT + t;
    const int mi = mask[xi];
    const float mf = (float)mi;
    const float x1 = mi ? x[xi] : xs1;
    a += w[0] * x1 + w[1] * mf + bdin[oc];
    xinb[(size_t)(b * 64 + oc) * NN + n] = __float2bfloat16(a);
    if (blockIdx.y == 0) { pred[xi] = xs1; x1buf[p] = x1; }
}

// gc = Wgc.d01 + bgc   grid (8,64)
__global__ __launch_bounds__(256) void k_gc(
    const float* __restrict__ d01, const float* __restrict__ Wgc, const float* __restrict__ bgc,
    float* __restrict__ gc)
{
    const int p = blockIdx.x * 256 + threadIdx.x;
    const int b = p >> 10, n = p & (NN - 1);
    const int oc = blockIdx.y;
    const float* dB = d01 + (size_t)b * 128 * NN + n;
    const float* w = Wgc + (size_t)oc * 128;
    float a = 0.f;
#pragma unroll 8
    for (int j = 0; j < 128; ++j) a += w[j] * dB[(size_t)j * NN];
    gc[(size_t)(b * 64 + oc) * NN + n] = a + bgc[oc];
}

// lo = prelu(Wlout.[gc,h] + blout); outb=lo; repr = [lo, h]   grid (8,64)
__global__ __launch_bounds__(256) void k_dec2(
    const float* __restrict__ gc, const float* __restrict__ h,
    const float* __restrict__ Wlout, const float* __restrict__ blout,
    const float* __restrict__ prelu_a,
    float* __restrict__ outb, float* __restrict__ repr, int t)
{
    const int p = blockIdx.x * 256 + threadIdx.x;
    const int b = p >> 10, n = p & (NN - 1);
    const int oc = blockIdx.y;
    const float* gB = gc + (size_t)b * 64 * NN + n;
    const float* hB = h + (size_t)b * 64 * NN + n;
    const float* w = Wlout + (size_t)oc * 128;
    float a = 0.f;
#pragma unroll 8
    for (int j = 0; j < 64; ++j) a += w[j] * gB[(size_t)j * NN];
#pragma unroll 8
    for (int j = 0; j < 64; ++j) a += w[64 + j] * hB[(size_t)j * NN];
    float v = a + blout[oc];
    v = (v >= 0.f) ? v : prelu_a[0] * v;
    outb[(size_t)(b * 64 + oc) * NN + n] = v;
    repr[(((size_t)b * 128 + oc) * NN + n) * TT + t] = v;
    repr[(((size_t)b * 128 + 64 + oc) * NN + n) * TT + t] = hB[(size_t)oc * NN];
}

// xs2 = Wro.[out,h] + bro; imp; x2 = mask ? x1 : xs2; write z ch0..66 fp32 + bf16
__global__ __launch_bounds__(256) void k_xs2(
    const float* __restrict__ outb, const float* __restrict__ h,
    const float* __restrict__ Wro, const float* __restrict__ bro,
    const float* __restrict__ x1buf, const float* __restrict__ x, const int* __restrict__ mask,
    float* __restrict__ imp, float* __restrict__ z, __hip_bfloat16* __restrict__ zb, int t)
{
    const int p = blockIdx.x * 256 + threadIdx.x;
    const int b = p >> 10, n = p & (NN - 1);
    const float* oB = outb + (size_t)b * 64 * NN + n;
    const float* hB = h + (size_t)b * 64 * NN + n;
    float acc = 0.f;
#pragma unroll 8
    for (int j = 0; j < 64; ++j) acc += Wro[j] * oB[(size_t)j * NN];
#pragma unroll 8
    for (int j = 0; j < 64; ++j) acc += Wro[64 + j] * hB[(size_t)j * NN];
    const float xs2 = acc + bro[0];
    const size_t xi = (size_t)(b * NN + n) * TT + t;
    imp[xi] = xs2;
    const int mi = mask[xi];
    const float mf = (float)mi;
    const float x2 = mi ? x1buf[p] : xs2;
    float* zB = z + (size_t)b * 330 * NN + n;
    __hip_bfloat16* zbB = zb + (size_t)b * 224 * NN + n;
    zB[0] = x2;           zbB[0] = __float2bfloat16(x2);
    zB[NN] = mf;          zbB[NN] = __float2bfloat16(mf);
#pragma unroll 8
    for (int j = 0; j < 64; ++j) {
        float hv = hB[(size_t)j * NN];
        zB[(size_t)(2 + j) * NN] = hv;
        zbB[(size_t)(2 + j) * NN] = __float2bfloat16(hv);
    }
}

// r,u = sigmoid(W.z + b); zc ch2..66 = r*h (fp32 + bf16); store u   grid (8,64)
__global__ __launch_bounds__(256) void k_gates(
    const float* __restrict__ z, const float* __restrict__ h,
    const float* __restrict__ Wr, const float* __restrict__ br,
    const float* __restrict__ Wu, const float* __restrict__ bu,
    float* __restrict__ ubuf, float* __restrict__ zc, __hip_bfloat16* __restrict__ zcb)
{
    const int p = blockIdx.x * 256 + threadIdx.x;
    const int b = p >> 10, n = p & (NN - 1);
    const int oc = blockIdx.y;
    const float* zB = z + (size_t)b * 330 * NN + n;
    const float* wr = Wr + (size_t)oc * 330;
    const float* wu = Wu + (size_t)oc * 330;
    float r = 0.f, u = 0.f;
#pragma unroll 10
    for (int j = 0; j < 330; ++j) {
        float zv = zB[(size_t)j * NN];
        r += wr[j] * zv; u += wu[j] * zv;
    }
    r = sigmoidf_(r + br[oc]);
    u = sigmoidf_(u + bu[oc]);
    const size_t hidx = (size_t)(b * 64 + oc) * NN + n;
    ubuf[hidx] = u;
    const float rh = r * h[hidx];
    zc[((size_t)b * 330 + 2 + oc) * NN + n] = rh;
    zcb[((size_t)b * 224 + 2 + oc) * NN + n] = __float2bfloat16(rh);
    if (blockIdx.y == 0) {
        float z0 = zB[0], z1 = zB[NN];
        zc[(size_t)b * 330 * NN + n] = z0;
        zc[((size_t)b * 330 + 1) * NN + n] = z1;
        zcb[(size_t)b * 224 * NN + n] = __float2bfloat16(z0);
        zcb[((size_t)b * 224 + 1) * NN + n] = __float2bfloat16(z1);
    }
}

// c = tanh(Wc.zc + bc); h = u*h + (1-u)*c   grid (8,64)
__global__ __launch_bounds__(256) void k_cell(
    const float* __restrict__ zc, const float* __restrict__ ubuf,
    const float* __restrict__ Wc, const float* __restrict__ bc,
    float* __restrict__ h)
{
    const int p = blockIdx.x * 256 + threadIdx.x;
    const int b = p >> 10, n = p & (NN - 1);
    const int oc = blockIdx.y;
    const float* zB = zc + (size_t)b * 330 * NN + n;
    const float* w = Wc + (size_t)oc * 330;
    float a = 0.f;
#pragma unroll 10
    for (int j = 0; j < 330; ++j) a += w[j] * zB[(size_t)j * NN];
    float c = tanhf(a + bc[oc]);
    const size_t idx = (size_t)(b * 64 + oc) * NN + n;
    const float u = ubuf[idx];
    h[idx] = u * h[idx] + (1.f - u) * c;
}

extern "C" void kernel_launch(void* const* d_in, const int* in_sizes, int n_in,
                              void* d_out, int out_size, void* d_ws, size_t ws_size,
                              hipStream_t stream)
{
    const float* x     = (const float*)d_in[0];
    const int*   mask  = (const int*)  d_in[1];
    const float* adj   = (const float*)d_in[2];
    const float* Wr    = (const float*)d_in[3];
    const float* br    = (const float*)d_in[4];
    const float* Wu    = (const float*)d_in[5];
    const float* bu    = (const float*)d_in[6];
    const float* Wc    = (const float*)d_in[7];
    const float* bc    = (const float*)d_in[8];
    const float* Wfs   = (const float*)d_in[9];
    const float* bfs   = (const float*)d_in[10];
    const float* Wdin  = (const float*)d_in[11];
    const float* bdin  = (const float*)d_in[12];
    const float* Wgc   = (const float*)d_in[13];
    const float* bgc   = (const float*)d_in[14];
    const float* Wlout = (const float*)d_in[15];
    const float* blout = (const float*)d_in[16];
    const float* Wro   = (const float*)d_in[17];
    const float* bro   = (const float*)d_in[18];
    const float* pa    = (const float*)d_in[19];

    float* ws = (float*)d_ws;
    float* h    = ws;                  // 131072
    float* d01  = ws + 131072;         // 262144
    float* gc   = ws + 393216;         // 131072
    float* outb = ws + 524288;         // 131072
    float* x1b  = ws + 655360;         // 2048
    float* z    = ws + 657408;         // 675840
    float* zc   = ws + 1333248;        // 675840
    float* ub   = ws + 2009088;        // 131072  -> fp32 end at 2140160 floats
    __hip_bfloat16* bfp  = (__hip_bfloat16*)(ws + 2140160);
    __hip_bfloat16* adjb = bfp;                    // 4194304
    __hip_bfloat16* xinb = bfp + 4194304;          // 131072
    __hip_bfloat16* zb   = bfp + 4325376;          // 2*224*1024 = 458752
    __hip_bfloat16* zcb  = bfp + 4784128;          // 458752  (bf16 end 5242880)

    float* imp  = (float*)d_out;
    float* pred = imp + (size_t)BB * NN * TT;
    float* repr = imp + (size_t)2 * BB * NN * TT;

    hipMemsetAsync(h, 0, (size_t)BB * 64 * NN * sizeof(float), stream);
    hipLaunchKernelGGL(k_cvt_adj, dim3(4096), dim3(256), 0, stream, adj, adjb);

    const dim3 gG(8, 64);   // GEMV grids
    const dim3 bG(256);
    const dim3 gM(16, 4);   // MFMA diffusion grid
    const dim3 bM(256);

    for (int t = 0; t < TT; ++t) {
        hipLaunchKernelGGL(k_prestep, gG, bG, 0, stream,
                           x, mask, h, Wfs, bfs, Wdin, bdin, xinb, x1b, pred, t);
        hipLaunchKernelGGL((k_dif<64>), gM, bM, 0, stream,
                           adjb, xinb, 64, 0, 0, d01, 128, 0, 64,
                           (__hip_bfloat16*)nullptr, 0, 0, 0);
        hipLaunchKernelGGL(k_gc, gG, bG, 0, stream, d01, Wgc, bgc, gc);
        hipLaunchKernelGGL(k_dec2, gG, bG, 0, stream,
                           gc, h, Wlout, blout, pa, outb, repr, t);
        hipLaunchKernelGGL(k_xs2, dim3(8), bG, 0, stream,
                           outb, h, Wro, bro, x1b, x, mask, imp, z, zb, t);
        hipLaunchKernelGGL((k_dif<66>), gM, bM, 0, stream,
                           adjb, zb, 224, 0, 0, z, 330, 66, 132, zb, 224, 66, 66);
        hipLaunchKernelGGL((k_dif<66>), gM, bM, 0, stream,
                           adjb, zb, 224, 66, 66, z, 330, 132, 132,
                           (__hip_bfloat16*)nullptr, 0, 0, 0);
        hipLaunchKernelGGL(k_gates, gG, bG, 0, stream,
                           z, h, Wr, br, Wu, bu, ub, zc, zcb);
        hipLaunchKernelGGL((k_dif<66>), gM, bM, 0, stream,
                           adjb, zcb, 224, 0, 0, zc, 330, 66, 132, zcb, 224, 66, 66);
        hipLaunchKernelGGL((k_dif<66>), gM, bM, 0, stream,
                           adjb, zcb, 224, 66, 66, zc, 330, 132, 132,
                           (__hip_bfloat16*)nullptr, 0, 0, 0);
        hipLaunchKernelGGL(k_cell, gG, bG, 0, stream, zc, ub, Wc, bc, h);
    }
}

// Round 4
// 1104.214 us; speedup vs baseline: 8.7928x; 1.9180x over previous
//
#include <hip/hip_runtime.h>
#include <hip/hip_bf16.h>
#include <cstddef>

#define NN 1024
#define BB 2
#define TT 12

typedef __attribute__((ext_vector_type(8))) short short8;
typedef __attribute__((ext_vector_type(4))) float f32x4;

__device__ __forceinline__ float sigmoidf_(float v) { return 1.0f / (1.0f + expf(-v)); }

// Convert adj (2*B*N*N fp32) to bf16 once per call.
__global__ __launch_bounds__(256) void k_cvt_adj(const float* __restrict__ a,
                                                 __hip_bfloat16* __restrict__ ab)
{
    size_t i = ((size_t)blockIdx.x * 256 + threadIdx.x) * 4;
    float4 v = *reinterpret_cast<const float4*>(a + i);
    ab[i + 0] = __float2bfloat16(v.x);
    ab[i + 1] = __float2bfloat16(v.y);
    ab[i + 2] = __float2bfloat16(v.z);
    ab[i + 3] = __float2bfloat16(v.w);
}

// One-time weight folds: Wcomb[o=s*64+oc][k] = sum_c Wgc[oc][s*64+c]*Wdin[c][k]
// bcomb[o] = sum_c Wgc[oc][s*64+c]*bdin[c];  blout2[oc] = blout[oc] + sum_j Wlout[oc][j]*bgc[j]
__global__ __launch_bounds__(256) void k_prep(
    const float* __restrict__ Wgc, const float* __restrict__ bgc,
    const float* __restrict__ Wdin, const float* __restrict__ bdin,
    const float* __restrict__ Wlout, const float* __restrict__ blout,
    float* __restrict__ Wcomb, float* __restrict__ bcomb, float* __restrict__ blout2)
{
    const int idx = blockIdx.x * 256 + threadIdx.x;
    if (idx < 128 * 66) {
        const int o = idx / 66, k = idx % 66;
        const float* g = Wgc + (size_t)(o & 63) * 128 + (o >> 6) * 64;
        float a = 0.f;
#pragma unroll 8
        for (int c = 0; c < 64; ++c) a += g[c] * Wdin[c * 66 + k];
        Wcomb[idx] = a;
    } else if (idx < 8448 + 128) {
        const int o = idx - 8448;
        const float* g = Wgc + (size_t)(o & 63) * 128 + (o >> 6) * 64;
        float a = 0.f;
#pragma unroll 8
        for (int c = 0; c < 64; ++c) a += g[c] * bdin[c];
        bcomb[o] = a;
    } else if (idx < 8448 + 128 + 64) {
        const int oc = idx - 8576;
        float a = blout[oc];
#pragma unroll 8
        for (int j = 0; j < 64; ++j) a += Wlout[(size_t)oc * 128 + j] * bgc[j];
        blout2[oc] = a;
    }
}

// Split-K MFMA diffusion. Block = 4 waves; wave kv covers K-chunk [kv*256, kv*256+256).
// Each block computes a 16-col (n) x C tile; cross-wave LDS reduce; wave 0 writes.
// dst[c][w] = sum_v src[c][v] * adj[sb][w][v]
template<int C>
__global__ __launch_bounds__(256) void k_dif(
    const __hip_bfloat16* __restrict__ adjb,
    const __hip_bfloat16* __restrict__ srcb, int srcCT, int srcOff, int srcStep,
    float* __restrict__ dstf, int dstfCT, int dstfOff, int dstfStep,
    __hip_bfloat16* __restrict__ dstb, int dstbCT, int dstbOff, int dstbStep)
{
    constexpr int MT = (C + 15) / 16;
    const int sb = blockIdx.y;
    const int s = sb >> 1, b = sb & 1;
    const int wave = threadIdx.x >> 6, lane = threadIdx.x & 63;
    const int lr = lane & 15, lq = lane >> 4;
    const int n0 = blockIdx.x * 16;

    const __hip_bfloat16* A = adjb + ((size_t)sb << 20) + (size_t)(n0 + lr) * NN + lq * 8;
    const __hip_bfloat16* X = srcb + ((size_t)(b * srcCT + srcOff + s * srcStep + lr)) * NN + lq * 8;

    f32x4 acc[MT];
#pragma unroll
    for (int m = 0; m < MT; ++m) acc[m] = (f32x4){0.f, 0.f, 0.f, 0.f};

    const short8 zsh = {0, 0, 0, 0, 0, 0, 0, 0};
    const int vbeg = wave * 256;
#pragma unroll 4
    for (int i = 0; i < 8; ++i) {
        const int v0 = vbeg + i * 32;
        short8 bfr = *reinterpret_cast<const short8*>(A + v0);
        short8 af[MT];
#pragma unroll
        for (int m = 0; m < MT; ++m) {
            short8 tv = *reinterpret_cast<const short8*>(X + (size_t)m * 16 * NN + v0);
            if ((C & 15) != 0 && m == MT - 1 && lr >= (C & 15)) tv = zsh;
            af[m] = tv;
        }
#pragma unroll
        for (int m = 0; m < MT; ++m)
            acc[m] = __builtin_amdgcn_mfma_f32_16x16x32_bf16(af[m], bfr, acc[m], 0, 0, 0);
    }

    __shared__ f32x4 red[3][MT][64];
    if (wave > 0) {
#pragma unroll
        for (int m = 0; m < MT; ++m) red[wave - 1][m][lane] = acc[m];
    }
    __syncthreads();
    if (wave == 0) {
#pragma unroll
        for (int m = 0; m < MT; ++m)
            acc[m] += red[0][m][lane] + red[1][m][lane] + red[2][m][lane];

        const size_t dbF = (size_t)(b * dstfCT + dstfOff + s * dstfStep);
        const size_t dbB = dstb ? (size_t)(b * dstbCT + dstbOff + s * dstbStep) : 0;
#pragma unroll
        for (int m = 0; m < MT; ++m) {
#pragma unroll
            for (int q = 0; q < 4; ++q) {
                const int c = m * 16 + lq * 4 + q;
                if (c < C) {
                    const float val = acc[m][q];
                    if (dstf) dstf[(dbF + c) * NN + n0 + lr] = val;
                    if (dstb) dstb[(dbB + c) * NN + n0 + lr] = __float2bfloat16(val);
                }
            }
        }
    }
}

// xs1 = Wfs.h + bfs ; x1 = mask ? x : xs1 ; y[o] = Wcomb[o].[x1,m,h] + bcomb[o]  (o = 0..127)
__global__ __launch_bounds__(256) void k_prestep(
    const float* __restrict__ x, const int* __restrict__ mask, const float* __restrict__ h,
    const float* __restrict__ Wfs, const float* __restrict__ bfs,
    const float* __restrict__ Wcomb, const float* __restrict__ bcomb,
    __hip_bfloat16* __restrict__ yb, float* __restrict__ x1buf, float* __restrict__ pred, int t)
{
    const int p = blockIdx.x * 256 + threadIdx.x;
    const int b = p >> 10, n = p & (NN - 1);
    const int o = blockIdx.y;
    const float* hB = h + (size_t)b * 64 * NN + n;
    const float* w = Wcomb + (size_t)o * 66;
    float a = 0.f, xs1 = 0.f;
#pragma unroll 8
    for (int j = 0; j < 64; ++j) {
        float hv = hB[(size_t)j * NN];
        xs1 += Wfs[j] * hv;
        a += w[2 + j] * hv;
    }
    xs1 += bfs[0];
    const size_t xi = (size_t)(b * NN + n) * TT + t;
    const int mi = mask[xi];
    const float mf = (float)mi;
    const float x1 = mi ? x[xi] : xs1;
    a += w[0] * x1 + w[1] * mf + bcomb[o];
    yb[(size_t)(b * 128 + o) * NN + n] = __float2bfloat16(a);
    if (blockIdx.y == 0) { pred[xi] = xs1; x1buf[p] = x1; }
}

// lo = prelu(Wlout.[gc0+gc1, h] + blout2); outb=lo; repr=[lo,h]; zb[2+oc]=bf16(h[oc])
__global__ __launch_bounds__(256) void k_dec2(
    const float* __restrict__ gcp, const float* __restrict__ h,
    const float* __restrict__ Wlout, const float* __restrict__ blout2,
    const float* __restrict__ prelu_a,
    float* __restrict__ outb, float* __restrict__ repr, __hip_bfloat16* __restrict__ zb, int t)
{
    const int p = blockIdx.x * 256 + threadIdx.x;
    const int b = p >> 10, n = p & (NN - 1);
    const int oc = blockIdx.y;
    const float* gB = gcp + (size_t)b * 128 * NN + n;
    const float* hB = h + (size_t)b * 64 * NN + n;
    const float* w = Wlout + (size_t)oc * 128;
    float a = 0.f;
#pragma unroll 8
    for (int j = 0; j < 64; ++j) {
        float gv = gB[(size_t)j * NN] + gB[(size_t)(64 + j) * NN];
        a += w[j] * gv;
        a += w[64 + j] * hB[(size_t)j * NN];
    }
    float v = a + blout2[oc];
    v = (v >= 0.f) ? v : prelu_a[0] * v;
    outb[(size_t)(b * 64 + oc) * NN + n] = v;
    repr[(((size_t)b * 128 + oc) * NN + n) * TT + t] = v;
    const float hv = hB[(size_t)oc * NN];
    repr[(((size_t)b * 128 + 64 + oc) * NN + n) * TT + t] = hv;
    zb[((size_t)b * 330 + 2 + oc) * NN + n] = __float2bfloat16(hv);
}

// xs2 via 64-lane shuffle reduce; imp; x2 = mask ? x1 : xs2; zb[0]=x2, zb[1]=mf
__global__ __launch_bounds__(256) void k_xs2r(
    const float* __restrict__ outb, const float* __restrict__ h,
    const float* __restrict__ Wro, const float* __restrict__ bro,
    const float* __restrict__ x1buf, const float* __restrict__ x, const int* __restrict__ mask,
    float* __restrict__ imp, __hip_bfloat16* __restrict__ zb, int t)
{
    const int nl = threadIdx.x >> 6, lane = threadIdx.x & 63;
    const int p = blockIdx.x * 4 + nl;
    const int b = p >> 10, n = p & (NN - 1);
    float v = Wro[lane] * outb[(size_t)(b * 64 + lane) * NN + n]
            + Wro[64 + lane] * h[(size_t)(b * 64 + lane) * NN + n];
#pragma unroll
    for (int off = 32; off > 0; off >>= 1) v += __shfl_xor(v, off);
    if (lane == 0) {
        const float xs2 = v + bro[0];
        const size_t xi = (size_t)(b * NN + n) * TT + t;
        imp[xi] = xs2;
        const int mi = mask[xi];
        const float x2 = mi ? x1buf[p] : xs2;
        zb[(size_t)b * 330 * NN + n] = __float2bfloat16(x2);
        zb[((size_t)b * 330 + 1) * NN + n] = __float2bfloat16((float)mi);
    }
}

// r,u = sigmoid(W.zb + b) (bf16 reads); zc[2+oc]=r*h fp32+bf16; ubuf=u; oc==0 copies ch0,1
__global__ __launch_bounds__(256) void k_gates(
    const __hip_bfloat16* __restrict__ zb, const float* __restrict__ h,
    const float* __restrict__ Wr, const float* __restrict__ br,
    const float* __restrict__ Wu, const float* __restrict__ bu,
    float* __restrict__ ubuf, float* __restrict__ zc, __hip_bfloat16* __restrict__ zcb)
{
    const int p = blockIdx.x * 256 + threadIdx.x;
    const int b = p >> 10, n = p & (NN - 1);
    const int oc = blockIdx.y;
    const __hip_bfloat16* zB = zb + (size_t)b * 330 * NN + n;
    const float* wr = Wr + (size_t)oc * 330;
    const float* wu = Wu + (size_t)oc * 330;
    float r = 0.f, u = 0.f;
#pragma unroll 10
    for (int j = 0; j < 330; ++j) {
        float zv = __bfloat162float(zB[(size_t)j * NN]);
        r += wr[j] * zv; u += wu[j] * zv;
    }
    r = sigmoidf_(r + br[oc]);
    u = sigmoidf_(u + bu[oc]);
    const size_t hidx = (size_t)(b * 64 + oc) * NN + n;
    ubuf[hidx] = u;
    const float rh = r * h[hidx];
    zc[((size_t)b * 330 + 2 + oc) * NN + n] = rh;
    zcb[((size_t)b * 330 + 2 + oc) * NN + n] = __float2bfloat16(rh);
    if (blockIdx.y == 0) {
        const __hip_bfloat16 z0 = zB[0], z1 = zB[NN];
        zc[(size_t)b * 330 * NN + n] = __bfloat162float(z0);
        zc[((size_t)b * 330 + 1) * NN + n] = __bfloat162float(z1);
        zcb[(size_t)b * 330 * NN + n] = z0;
        zcb[((size_t)b * 330 + 1) * NN + n] = z1;
    }
}

// c = tanh(Wc.zc + bc); h = u*h + (1-u)*c   (fp32 reads for h accuracy)
__global__ __launch_bounds__(256) void k_cell(
    const float* __restrict__ zc, const float* __restrict__ ubuf,
    const float* __restrict__ Wc, const float* __restrict__ bc,
    float* __restrict__ h)
{
    const int p = blockIdx.x * 256 + threadIdx.x;
    const int b = p >> 10, n = p & (NN - 1);
    const int oc = blockIdx.y;
    const float* zB = zc + (size_t)b * 330 * NN + n;
    const float* w = Wc + (size_t)oc * 330;
    float a = 0.f;
#pragma unroll 10
    for (int j = 0; j < 330; ++j) a += w[j] * zB[(size_t)j * NN];
    const float c = tanhf(a + bc[oc]);
    const size_t idx = (size_t)(b * 64 + oc) * NN + n;
    const float u = ubuf[idx];
    h[idx] = u * h[idx] + (1.f - u) * c;
}

extern "C" void kernel_launch(void* const* d_in, const int* in_sizes, int n_in,
                              void* d_out, int out_size, void* d_ws, size_t ws_size,
                              hipStream_t stream)
{
    const float* x     = (const float*)d_in[0];
    const int*   mask  = (const int*)  d_in[1];
    const float* adj   = (const float*)d_in[2];
    const float* Wr    = (const float*)d_in[3];
    const float* br    = (const float*)d_in[4];
    const float* Wu    = (const float*)d_in[5];
    const float* bu    = (const float*)d_in[6];
    const float* Wc    = (const float*)d_in[7];
    const float* bc    = (const float*)d_in[8];
    const float* Wfs   = (const float*)d_in[9];
    const float* bfs   = (const float*)d_in[10];
    const float* Wdin  = (const float*)d_in[11];
    const float* bdin  = (const float*)d_in[12];
    const float* Wgc   = (const float*)d_in[13];
    const float* bgc   = (const float*)d_in[14];
    const float* Wlout = (const float*)d_in[15];
    const float* blout = (const float*)d_in[16];
    const float* Wro   = (const float*)d_in[17];
    const float* bro   = (const float*)d_in[18];
    const float* pa    = (const float*)d_in[19];

    float* ws = (float*)d_ws;
    float* h      = ws;                 // 131072
    float* gcp    = ws + 131072;        // 262144
    float* outb   = ws + 393216;        // 131072
    float* x1b    = ws + 524288;        // 2048
    float* zc     = ws + 526336;        // 675840
    float* ub     = ws + 1202176;       // 131072
    float* Wcomb  = ws + 1333248;       // 8448
    float* bcomb  = ws + 1341696;       // 128
    float* blout2 = ws + 1341824;       // 64 -> fp32 end 1341888
    __hip_bfloat16* bfp  = (__hip_bfloat16*)(ws + 1341888);
    __hip_bfloat16* adjb = bfp;                    // 4194304
    __hip_bfloat16* yb   = bfp + 4194304;          // 262144
    __hip_bfloat16* zb   = bfp + 4456448;          // 675840
    __hip_bfloat16* zcb  = bfp + 5132288;          // 675840 (bf16 end 5808128)

    float* imp  = (float*)d_out;
    float* pred = imp + (size_t)BB * NN * TT;
    float* repr = imp + (size_t)2 * BB * NN * TT;

    hipMemsetAsync(h, 0, (size_t)BB * 64 * NN * sizeof(float), stream);
    hipLaunchKernelGGL(k_prep, dim3(34), dim3(256), 0, stream,
                       Wgc, bgc, Wdin, bdin, Wlout, blout, Wcomb, bcomb, blout2);
    hipLaunchKernelGGL(k_cvt_adj, dim3(4096), dim3(256), 0, stream, adj, adjb);

    const dim3 gM(64, 4);   // diffusion: 64 n-tiles x 4 (s,b), 4-wave split-K blocks
    const dim3 bM(256);
    const dim3 gG(8, 64);
    const dim3 gP(8, 128);
    const dim3 bG(256);

    for (int t = 0; t < TT; ++t) {
        hipLaunchKernelGGL(k_prestep, gP, bG, 0, stream,
                           x, mask, h, Wfs, bfs, Wcomb, bcomb, yb, x1b, pred, t);
        hipLaunchKernelGGL((k_dif<64>), gM, bM, 0, stream,
                           adjb, yb, 128, 0, 64, gcp, 128, 0, 64,
                           (__hip_bfloat16*)nullptr, 0, 0, 0);
        hipLaunchKernelGGL(k_dec2, gG, bG, 0, stream,
                           gcp, h, Wlout, blout2, pa, outb, repr, zb, t);
        hipLaunchKernelGGL(k_xs2r, dim3(512), bG, 0, stream,
                           outb, h, Wro, bro, x1b, x, mask, imp, zb, t);
        hipLaunchKernelGGL((k_dif<66>), gM, bM, 0, stream,
                           adjb, zb, 330, 0, 0, (float*)nullptr, 0, 0, 0, zb, 330, 66, 132);
        hipLaunchKernelGGL((k_dif<66>), gM, bM, 0, stream,
                           adjb, zb, 330, 66, 132, (float*)nullptr, 0, 0, 0, zb, 330, 132, 132);
        hipLaunchKernelGGL(k_gates, gG, bG, 0, stream,
                           zb, h, Wr, br, Wu, bu, ub, zc, zcb);
        hipLaunchKernelGGL((k_dif<66>), gM, bM, 0, stream,
                           adjb, zcb, 330, 0, 0, zc, 330, 66, 132, zcb, 330, 66, 132);
        hipLaunchKernelGGL((k_dif<66>), gM, bM, 0, stream,
                           adjb, zcb, 330, 66, 132, zc, 330, 132, 132,
                           (__hip_bfloat16*)nullptr, 0, 0, 0);
        hipLaunchKernelGGL(k_cell, gG, bG, 0, stream, zc, ub, Wc, bc, h);
    }
}